// Round 9
// baseline (220.929 us; speedup 1.0000x reference)
//
#include <hip/hip_runtime.h>
#include <math.h>

#define Hh 12
#define S_LEN 2048
#define D_MODEL 768
#define HD 64

static constexpr float MAXLS = 4.6051701859880914f; // log(1/0.01)
static constexpr float LOG2E = 1.4426950408889634f;

typedef short bf16x8 __attribute__((ext_vector_type(8)));
typedef float f32x4  __attribute__((ext_vector_type(4)));
typedef float f32x16 __attribute__((ext_vector_type(16)));
typedef unsigned short u16x4 __attribute__((ext_vector_type(4)));
typedef unsigned short u16x8 __attribute__((ext_vector_type(8)));
typedef unsigned int u32x4 __attribute__((ext_vector_type(4)));

__device__ __forceinline__ unsigned short f2bf(float x) {
    unsigned int u = __builtin_bit_cast(unsigned int, x);
    unsigned int r = (u + 0x7FFF + ((u >> 16) & 1)) >> 16;
    return (unsigned short)r;
}

__device__ __forceinline__ unsigned int cvtpk(float a, float b) {
    unsigned int r;
    asm("v_cvt_pk_bf16_f32 %0, %1, %2" : "=v"(r) : "v"(a), "v"(b));
    return r;
}

__device__ __forceinline__ void gload16(const void* g, void* l) {
    __builtin_amdgcn_global_load_lds(
        (const __attribute__((address_space(1))) unsigned int*)g,
        (__attribute__((address_space(3))) unsigned int*)l, 16, 0, 0);
}

// ---------------- fp32 -> bf16 convert: hs, Wq|Wk|Wv (concat), Wo ----------------
__global__ __launch_bounds__(256)
void convert_bf16(const float* __restrict__ hs,
                  const float* __restrict__ Wq, const float* __restrict__ Wk,
                  const float* __restrict__ Wv, const float* __restrict__ Wo,
                  unsigned short* __restrict__ hsb,
                  unsigned short* __restrict__ wqkvb,
                  unsigned short* __restrict__ wob)
{
    const long long N0 = 8192LL * 768;
    const long long NW = 768LL * 768;
    const long long e  = ((long long)blockIdx.x * 256 + threadIdx.x) * 8;
    const float* src; unsigned short* dst;
    if (e < N0) { src = hs + e; dst = hsb + e; }
    else if (e < N0 + 3*NW) {
        const long long r = e - N0;
        const int z = (int)(r / NW);
        src = (z == 0 ? Wq : z == 1 ? Wk : Wv) + (r - (long long)z * NW);
        dst = wqkvb + r;
    } else {
        const long long r = e - N0 - 3*NW;
        src = Wo + r; dst = wob + r;
    }
    const float4 f0 = *(const float4*)src;
    const float4 f1 = *(const float4*)(src + 4);
    u16x8 o;
    o[0]=f2bf(f0.x); o[1]=f2bf(f0.y); o[2]=f2bf(f0.z); o[3]=f2bf(f0.w);
    o[4]=f2bf(f1.x); o[5]=f2bf(f1.y); o[6]=f2bf(f1.z); o[7]=f2bf(f1.w);
    *(u16x8*)dst = o;
}

// ---------------- bf16 MFMA GEMM: C = A @ W^T (+bias) ----------------
// MODE 0 (BN=128, QKV, N=2304):
//   z<2: fused L2-norm -> bf16 [B,H,S,64], permuted d' = ll*4+j; q scaled
//        by exp(min(ls,log100))*log2e.
//   z==2: bf16 V^T -> [B,H,64,S] via LDS transpose (coalesced stores), kv
//        bits 2<->3 swapped within each 64-block of s.
// MODE 1 (BN=64): fp32 out[m][768] + bias.
template<int MODE, int BN, int NWGX>
__global__ __launch_bounds__(256)
void gemm_bf16(const unsigned short* __restrict__ A,
               const unsigned short* __restrict__ Wt,
               const float* __restrict__ b0, const float* __restrict__ b1,
               const float* __restrict__ b2, const float* __restrict__ ls,
               unsigned short* __restrict__ qb, unsigned short* __restrict__ kb,
               unsigned short* __restrict__ vt, float* __restrict__ out)
{
    constexpr int K  = 768;
    constexpr int JW = BN / 32;            // B j-frags per wave
    __shared__ char As[16384];
    __shared__ char Bs[BN * 128];

    // bijective XCD-chunked swizzle (grid = NWGX*64, multiple of 8)
    constexpr int CPX = (NWGX * 64) / 8;
    const int bid = blockIdx.x;
    const int wg  = (bid & 7) * CPX + (bid >> 3);
    const int n0  = (wg % NWGX) * BN;
    const int m0  = (wg / NWGX) * 128;

    const int tid = threadIdx.x, w = tid >> 6, l = tid & 63;
    const int wr = w >> 1, wc = w & 1, hi = l >> 4, ll = l & 15;

    const int srow = l >> 3;
    const int sch  = (l & 7) ^ srow;
    const char* Ab = (const char*)(A  + (size_t)(m0 + w*32) * K) + srow * (K*2) + sch * 16;
    const char* Bb = (const char*)(Wt + (size_t)(n0 + w*(BN/4)) * K) + srow * (K*2) + sch * 16;
    char* AsW = As + (w*32) * 128;
    char* BsW = Bs + (w*(BN/4)) * 128;

    f32x4 acc[4][JW];
    #pragma unroll
    for (int i = 0; i < 4; ++i)
        #pragma unroll
        for (int j = 0; j < JW; ++j) acc[i][j] = (f32x4){0.f,0.f,0.f,0.f};

    for (int kt = 0; kt < K/64; ++kt) {
        __syncthreads();
        #pragma unroll
        for (int s = 0; s < 4; ++s)
            gload16(Ab + kt*128 + s*8*(K*2), AsW + s*1024);
        #pragma unroll
        for (int s = 0; s < JW; ++s)
            gload16(Bb + kt*128 + s*8*(K*2), BsW + s*1024);
        __syncthreads();

        bf16x8 af[2][4], bf[2][JW];
        #pragma unroll
        for (int kk = 0; kk < 2; ++kk) {
            const int pc = kk*4 + hi;
            #pragma unroll
            for (int i = 0; i < 4; ++i) {
                const int ra = wr*64 + i*16 + ll;
                af[kk][i] = *(const bf16x8*)(As + ra*128 + ((pc ^ (ra & 7)) << 4));
            }
            #pragma unroll
            for (int j = 0; j < JW; ++j) {
                const int rb = wc*(BN/2) + j*16 + ll;
                bf[kk][j] = *(const bf16x8*)(Bs + rb*128 + ((pc ^ (rb & 7)) << 4));
            }
        }
        #pragma unroll
        for (int kk = 0; kk < 2; ++kk)
            #pragma unroll
            for (int i = 0; i < 4; ++i)
                #pragma unroll
                for (int j = 0; j < JW; ++j)
                    acc[i][j] = __builtin_amdgcn_mfma_f32_16x16x32_bf16(af[kk][i], bf[kk][j], acc[i][j], 0, 0, 0);
    }

    if (MODE == 0) {
        const int z  = n0 / 768;
        const int nl = (n0 % 768) + wc*64;
        const int h  = nl >> 6;
        const int b  = m0 >> 11;
        const int s0 = (m0 & (S_LEN-1)) + wr*64;
        const float* bias = (z == 0) ? b0 : (z == 1) ? b1 : b2;
        float bj[4];
        #pragma unroll
        for (int j = 0; j < 4; ++j) bj[j] = bias[nl + j*16 + ll];

        if (z < 2) {
            const float sc = (z == 0) ? expf(fminf(ls[h], MAXLS)) * LOG2E : 1.0f;
            unsigned short* dst = (z == 0 ? qb : kb) + ((size_t)(b*Hh + h) * S_LEN) * HD;
            #pragma unroll
            for (int i = 0; i < 4; ++i) {
                float vv[4][4]; float ss[4] = {0.f, 0.f, 0.f, 0.f};
                #pragma unroll
                for (int r = 0; r < 4; ++r)
                    #pragma unroll
                    for (int j = 0; j < 4; ++j) {
                        const float x = acc[i][j][r] + bj[j];
                        vv[r][j] = x; ss[r] += x * x;
                    }
                #pragma unroll
                for (int mm = 1; mm < 16; mm <<= 1) {
                    ss[0] += __shfl_xor(ss[0], mm, 64);
                    ss[1] += __shfl_xor(ss[1], mm, 64);
                    ss[2] += __shfl_xor(ss[2], mm, 64);
                    ss[3] += __shfl_xor(ss[3], mm, 64);
                }
                #pragma unroll
                for (int r = 0; r < 4; ++r) {
                    const float inv = sc / fmaxf(sqrtf(ss[r]), 1e-12f);
                    const int s = s0 + i*16 + hi*4 + r;
                    u16x4 o;
                    #pragma unroll
                    for (int j = 0; j < 4; ++j) o[j] = f2bf(vv[r][j] * inv);
                    *(u16x4*)(dst + (size_t)s * HD + ll*4) = o;   // d' = ll*4+j
                }
            }
        } else {
            // V^T via LDS transpose. kv-permutation (swap s bits 2,3) folded
            // into the LDS write position; reads/stores fully linear.
            __syncthreads();   // all waves done with As/Bs K-loop reads (z uniform per block)
            char* T = (w < 2 ? As : Bs) + (w & 1) * 8192;   // [64 d][64 s] bf16, chunk-XOR swz
            const int ch_add = hi & 1;     // (hsw>>1)
            const int half8  = hi >> 1;    // (hsw&1)*8 bytes
            #pragma unroll
            for (int j = 0; j < 4; ++j) {
                const int d = j*16 + ll;
                #pragma unroll
                for (int i = 0; i < 4; ++i) {
                    u16x4 o;
                    #pragma unroll
                    for (int r = 0; r < 4; ++r) o[r] = f2bf(acc[i][j][r] + bj[j]);
                    const int byteoff = d*128 + (((i*2 + ch_add) ^ (d & 7)) << 4) + half8*8;
                    *(u16x4*)(T + byteoff) = o;
                }
            }
            // wave-local readback (compiler inserts lgkmcnt) -> coalesced stores
            const int dl = l >> 2;
            #pragma unroll
            for (int dp = 0; dp < 4; ++dp) {
                const int d = dp*16 + dl;
                unsigned short* vrow = vt + ((size_t)(b*Hh + h) * HD + d) * S_LEN + s0;
                #pragma unroll
                for (int rep = 0; rep < 2; ++rep) {
                    const int c = (l & 3) + rep*4;
                    const u16x8 vv = *(const u16x8*)(T + d*128 + ((c ^ (d & 7)) << 4));
                    *(u16x8*)(vrow + c*8) = vv;
                }
            }
        }
    } else {
        #pragma unroll
        for (int i = 0; i < 4; ++i)
            #pragma unroll
            for (int j = 0; j < JW; ++j) {
                const int n = n0 + wc*(BN/2) + j*16 + ll;
                const float bn = b0[n];
                #pragma unroll
                for (int r = 0; r < 4; ++r) {
                    const int m = m0 + wr*64 + i*16 + hi*4 + r;
                    out[(size_t)m * D_MODEL + n] = acc[i][j][r] + bn;
                }
            }
    }
}

// ---------------- Flash attention v6: 64 q/wave, 2-wave blocks ----------------
// Each kf/vf LDS read now feeds 2 MFMAs (shared across the wave's 2 q-frags):
// per wave-tile 16 ds_read_b128 / 32 MFMA (was 24/20) -> LDS-BW no longer binding.
// lsum on VALU (lane owns q-col; complementary kv-half in lane^32).
// Double-buffered LDS (2 x 16KB), prefetch before compute, 1 barrier/tile.
__global__ __launch_bounds__(128, 2)
void attn_mfma6(const char* __restrict__ qb_, const char* __restrict__ kb_,
                const char* __restrict__ vtb_,
                unsigned short* __restrict__ ctx)
{
    __shared__ char smem[32768];
    constexpr int NT = S_LEN / 64;

    const int flat = blockIdx.x;          // 0..767
    const int xcd = flat & 7, ix = flat >> 3;
    const int bh = xcd * 6 + (ix >> 4);   // 6 bh per XCD
    const int q0 = (ix & 15) * 128;
    const int b = bh / Hh, h = bh % Hh;

    const int tid = threadIdx.x, w = tid >> 6, l = tid & 63;
    const int lq = l & 31, g = l >> 5;

    const char* qg = qb_ + ((size_t)bh * S_LEN + q0 + w * 64) * 128;
    const char* kg = kb_ + (size_t)bh * S_LEN * 128 + (size_t)l * 128;        // lane = kv row
    const char* vg = vtb_ + (size_t)bh * HD * (S_LEN * 2) + (size_t)l * 4096; // lane = d row

    // 2 q-frags per wave: cols w*64 + f*32 + lq
    bf16x8 qf0[4], qf1[4];
    #pragma unroll
    for (int s = 0; s < 4; ++s) {
        qf0[s] = *(const bf16x8*)(qg + (size_t)lq * 128 + s * 32 + g * 16);
        qf1[s] = *(const bf16x8*)(qg + (size_t)(32 + lq) * 128 + s * 32 + g * 16);
    }

    f32x16 acc00, acc01, acc10, acc11;    // [f][dblk]
    #pragma unroll
    for (int i = 0; i < 16; ++i) { acc00[i]=0.f; acc01[i]=0.f; acc10[i]=0.f; acc11[i]=0.f; }
    float lsum0 = 0.f, lsum1 = 0.f;

    // wave w stages chunks {4w..4w+3} of K and V (8 gload16/wave/tile)
#define STAGE(bi, kt) do {                                                    \
        char* dS = smem + ((bi) << 14);                                       \
        gload16(kg + (size_t)(kt)*8192 + (4*w+0)*16, dS + (4*w+0)*1024);      \
        gload16(kg + (size_t)(kt)*8192 + (4*w+1)*16, dS + (4*w+1)*1024);      \
        gload16(kg + (size_t)(kt)*8192 + (4*w+2)*16, dS + (4*w+2)*1024);      \
        gload16(kg + (size_t)(kt)*8192 + (4*w+3)*16, dS + (4*w+3)*1024);      \
        gload16(vg + (size_t)(kt)*128 + (4*w+0)*16, dS + 8192 + (4*w+0)*1024);\
        gload16(vg + (size_t)(kt)*128 + (4*w+1)*16, dS + 8192 + (4*w+1)*1024);\
        gload16(vg + (size_t)(kt)*128 + (4*w+2)*16, dS + 8192 + (4*w+2)*1024);\
        gload16(vg + (size_t)(kt)*128 + (4*w+3)*16, dS + 8192 + (4*w+3)*1024);\
    } while (0)

    STAGE(0, 0);
    __syncthreads();
    int cur = 0;

    for (int kt = 0; kt < NT; ++kt) {
        if (kt + 1 < NT) STAGE(cur ^ 1, kt + 1);    // prefetch next tile
        const char* Ks = smem + (cur << 14);
        const char* Vs = Ks + 8192;

        // S^T = K . Q^T : each kf read feeds both q-frags
        f32x16 sa00, sa01, sa10, sa11;    // [kvblk][f]
        #pragma unroll
        for (int i = 0; i < 16; ++i) { sa00[i]=0.f; sa01[i]=0.f; sa10[i]=0.f; sa11[i]=0.f; }

        __builtin_amdgcn_s_setprio(1);
        #pragma unroll
        for (int s = 0; s < 4; ++s) {
            const bf16x8 kf0 = *(const bf16x8*)(Ks + (2*s + g) * 1024 + lq * 16);
            const bf16x8 kf1 = *(const bf16x8*)(Ks + (2*s + g) * 1024 + 512 + lq * 16);
            sa00 = __builtin_amdgcn_mfma_f32_32x32x16_bf16(kf0, qf0[s], sa00, 0, 0, 0);
            sa01 = __builtin_amdgcn_mfma_f32_32x32x16_bf16(kf0, qf1[s], sa01, 0, 0, 0);
            sa10 = __builtin_amdgcn_mfma_f32_32x32x16_bf16(kf1, qf0[s], sa10, 0, 0, 0);
            sa11 = __builtin_amdgcn_mfma_f32_32x32x16_bf16(kf1, qf1[s], sa11, 0, 0, 0);
        }
        __builtin_amdgcn_s_setprio(0);

        // softmax (p = exp2(s), scale folded into q) + PV; vf shared across frags
        #pragma unroll
        for (int t = 0; t < 4; ++t) {
            float p0[8], p1[8];
            #pragma unroll
            for (int e = 0; e < 8; ++e) {
                const float s0v = (t & 2) ? sa10[8*(t&1) + e] : sa00[8*(t&1) + e];
                const float s1v = (t & 2) ? sa11[8*(t&1) + e] : sa01[8*(t&1) + e];
                p0[e] = __builtin_amdgcn_exp2f(s0v);
                p1[e] = __builtin_amdgcn_exp2f(s1v);
            }
            lsum0 += ((p0[0]+p0[1]) + (p0[2]+p0[3])) + ((p0[4]+p0[5]) + (p0[6]+p0[7]));
            lsum1 += ((p1[0]+p1[1]) + (p1[2]+p1[3])) + ((p1[4]+p1[5]) + (p1[6]+p1[7]));
            u32x4 u0, u1;
            u0[0] = cvtpk(p0[0], p0[1]); u0[1] = cvtpk(p0[2], p0[3]);
            u0[2] = cvtpk(p0[4], p0[5]); u0[3] = cvtpk(p0[6], p0[7]);
            u1[0] = cvtpk(p1[0], p1[1]); u1[1] = cvtpk(p1[2], p1[3]);
            u1[2] = cvtpk(p1[4], p1[5]); u1[3] = cvtpk(p1[6], p1[7]);
            const bf16x8 pa0 = __builtin_bit_cast(bf16x8, u0);
            const bf16x8 pa1 = __builtin_bit_cast(bf16x8, u1);

            const bf16x8 vf0 = *(const bf16x8*)(Vs + (2*t + g) * 1024 + lq * 16);
            const bf16x8 vf1 = *(const bf16x8*)(Vs + (2*t + g) * 1024 + 512 + lq * 16);
            __builtin_amdgcn_s_setprio(1);
            acc00 = __builtin_amdgcn_mfma_f32_32x32x16_bf16(pa0, vf0, acc00, 0, 0, 0);
            acc01 = __builtin_amdgcn_mfma_f32_32x32x16_bf16(pa0, vf1, acc01, 0, 0, 0);
            acc10 = __builtin_amdgcn_mfma_f32_32x32x16_bf16(pa1, vf0, acc10, 0, 0, 0);
            acc11 = __builtin_amdgcn_mfma_f32_32x32x16_bf16(pa1, vf1, acc11, 0, 0, 0);
            __builtin_amdgcn_s_setprio(0);
        }

        __syncthreads();    // drains prefetch; frees cur for restage
        cur ^= 1;
    }
#undef STAGE

    // epilogue: combine kv-halves, broadcast lsum per q-row, write ctx bf16
    lsum0 += __shfl_xor(lsum0, 32, 64);
    lsum1 += __shfl_xor(lsum1, 32, 64);
    #pragma unroll
    for (int r = 0; r < 16; ++r) {
        const int qrow = (r & 3) + 8 * (r >> 2) + 4 * g;
        const float i0 = 1.0f / __shfl(lsum0, qrow, 64);
        const float i1 = 1.0f / __shfl(lsum1, qrow, 64);
        unsigned short* c0 = ctx + ((size_t)b * S_LEN + q0 + w * 64 + qrow) * D_MODEL + h * HD;
        unsigned short* c1 = ctx + ((size_t)b * S_LEN + q0 + w * 64 + 32 + qrow) * D_MODEL + h * HD;
        c0[lq]      = f2bf(acc00[r] * i0);
        c0[32 + lq] = f2bf(acc01[r] * i0);
        c1[lq]      = f2bf(acc10[r] * i1);
        c1[32 + lq] = f2bf(acc11[r] * i1);
    }
}

extern "C" void kernel_launch(void* const* d_in, const int* in_sizes, int n_in,
                              void* d_out, int out_size, void* d_ws, size_t ws_size,
                              hipStream_t stream)
{
    const float* hs = (const float*)d_in[0];
    const float* Wq = (const float*)d_in[1];
    const float* bq = (const float*)d_in[2];
    const float* Wk = (const float*)d_in[3];
    const float* bk = (const float*)d_in[4];
    const float* Wv = (const float*)d_in[5];
    const float* bv = (const float*)d_in[6];
    const float* Wo = (const float*)d_in[7];
    const float* bo = (const float*)d_in[8];
    const float* ls = (const float*)d_in[9];
    float* out = (float*)d_out;

    const int B = 4;
    const size_t nHS = 8192ULL * 768;
    const size_t nW  = 768ULL * 768;
    const size_t nPB = (size_t)B * Hh * S_LEN * HD;

    unsigned short* hsb   = (unsigned short*)d_ws;
    unsigned short* wqkvb = hsb + nHS;
    unsigned short* wob   = wqkvb + 3 * nW;
    unsigned short* qbuf  = wob + nW;
    unsigned short* kbuf  = qbuf + nPB;
    unsigned short* vtb   = kbuf + nPB;
    unsigned short* cbuf  = vtb + nPB;

    hipLaunchKernelGGL(convert_bf16, dim3(4224), dim3(256), 0, stream,
                       hs, Wq, Wk, Wv, Wo, hsb, wqkvb, wob);

    hipLaunchKernelGGL((gemm_bf16<0, 128, 18>), dim3(18 * 64), dim3(256), 0, stream,
                       hsb, wqkvb, bq, bk, bv, ls, qbuf, kbuf, vtb, nullptr);

    hipLaunchKernelGGL(attn_mfma6, dim3((S_LEN/128) * B * Hh), dim3(128), 0, stream,
                       (const char*)qbuf, (const char*)kbuf, (const char*)vtb, cbuf);

    hipLaunchKernelGGL((gemm_bf16<1, 64, 12>), dim3(12 * 64), dim3(256), 0, stream,
                       cbuf, wob, bo, nullptr, nullptr, nullptr,
                       nullptr, nullptr, nullptr, out);
}